// Round 5
// baseline (32909.000 us; speedup 1.0000x reference)
//
#include <hip/hip_runtime.h>
#include <math.h>

// Problem sizes (fixed by reference)
#define TT 2048
#define IIN 128
#define HHID 512
#define OOUT 64
#define OUT_OFF (64 * HHID)   // h_final [B,H] then outs [B,T,O]

// 16 groups x 16 WGs. Group g owns batches 4g..4g+3. WG w owns h-rows
// [32w,32w+32) + Who rows [4w,4w+4). 4 waves/WG; wave wv owns 8 h-rows +
// Who row 4w+wv; lane l owns k-chunk [8l,8l+8). Weights in VGPRs.
// th exchange: producers store scalar relaxed-agent atomics; consumers stage
// 8KB/WG/step via coalesced dwordx4 sc0sc1 loads -> swizzled LDS -> b128 reads.
// Sync: per-group epoch counter. ONE lane (tid0) polls via sc0sc1 bypass load,
// __syncthreads releases the WG (R4 lesson: all-wave polling self-congests the
// MALL and burns VALU; R2 lesson: no acquire/release fences in the loop).
#define NTHR 256

typedef float f32x4 __attribute__((ext_vector_type(4)));

__device__ __forceinline__ void load2_bypass(const float* p0, const float* p1,
                                             f32x4& a, f32x4& b) {
  asm volatile("global_load_dwordx4 %0, %2, off sc0 sc1\n\t"
               "global_load_dwordx4 %1, %3, off sc0 sc1"
               : "=v"(a), "=v"(b) : "v"(p0), "v"(p1) : "memory");
}

// float-index swizzle: XOR chunk bits[2:4] with row bits (row = f>>5)
__device__ __forceinline__ int swzF(int f) {
  return f ^ (((f >> 5) & 7) << 2);
}

extern "C" __global__ void __launch_bounds__(NTHR, 1)
rnn_kernel(const float* __restrict__ inputs,
           const float* __restrict__ hidden,
           const float* __restrict__ in_noise,
           const float* __restrict__ re_noise,
           const float* __restrict__ Wih,
           const float* __restrict__ Whh,
           const float* __restrict__ bhh,
           const float* __restrict__ Who,
           const float* __restrict__ bho,
           float* __restrict__ out,
           unsigned int* __restrict__ cnt,    // [16] epoch counters, 64-dword stride
           float* __restrict__ th_buf)        // [2][16][4][512] f32
{
  __shared__ float lds_th[2][2048];   // double-buffered swizzled th tile
  __shared__ unsigned s_arrive;

  const int tid = threadIdx.x;
  const int l  = tid & 63;
  const int wv = tid >> 6;               // wave 0..3
  const int g = blockIdx.x & 15;         // group (bid%16 -> XCD affinity, perf only)
  const int w = blockIdx.x >> 4;         // member 0..15
  const int j0 = w * 32;
  const int k0 = 8 * l;

  // ---------------- weights into registers (cached loads, once) ----------------
  f32x4 whh[8][2];
  float2 wih[8];
  #pragma unroll
  for (int r = 0; r < 8; ++r) {
    const float* wr = &Whh[(long)(j0 + 8 * wv + r) * HHID + k0];
    whh[r][0] = *(const f32x4*)wr;
    whh[r][1] = *(const f32x4*)(wr + 4);
    wih[r] = *(const float2*)&Wih[(long)(j0 + 8 * wv + r) * IIN + 2 * l];
  }
  const int oc = 4 * w + wv;
  f32x4 who0 = *(const f32x4*)&Who[(long)oc * HHID + k0];
  f32x4 who1 = *(const f32x4*)&Who[(long)oc * HHID + k0 + 4];
  const float bho_v = bho[oc];

  // ---------------- reduce-output lane mapping ----------------
  const bool redlane = (l & 1) == 0;
  const int v  = (l >> 1) & 31;
  const int rr = v >> 2;                 // local h row 0..7
  const int bb = v & 3;                  // batch
  const int grow = j0 + 8 * wv + rr;
  const int ob = (l >> 4) & 3;
  const bool outlane = (l & 15) == 0;

  if (tid == 0) s_arrive = 0;

  float bhh_v = 0.f, hreg = 0.f;
  if (redlane) {
    bhh_v = bhh[grow];
    hreg = hidden[(long)(4 * g + bb) * HHID + grow];
    __hip_atomic_store(&th_buf[((0 * 16 + g) * 4 + bb) * HHID + grow],
                       tanhf(hreg), __ATOMIC_RELAXED, __HIP_MEMORY_SCOPE_AGENT);
  }
  __syncthreads();                       // drains vmcnt; s_arrive visible
  if (tid == 0)
    __hip_atomic_fetch_add(&cnt[g * 64], 1u, __ATOMIC_RELAXED,
                           __HIP_MEMORY_SCOPE_AGENT);

  // staging indices
  const int stg0 = swzF(4 * tid);
  const int stg1 = swzF(4 * tid + 1024);
  // read swizzle XOR term: f0 = (512b + 8l) ^ rsw
  const int rsw = ((l >> 2) & 7) << 2;

  const unsigned int* cptr = &cnt[g * 64];

  for (int t = 0; t <= TT; ++t) {
    // ---- prefetch x / noise (cached loads; latency hidden under spin) ----
    float2 xi[4], xn[4];
    float nre = 0.f;
    if (t < TT) {
      #pragma unroll
      for (int b = 0; b < 4; ++b) {
        long off = ((long)(4 * g + b) * TT + t) * IIN + 2 * l;
        xi[b] = *(const float2*)&inputs[off];
        xn[b] = *(const float2*)&in_noise[off];
      }
      if (redlane)
        nre = re_noise[((long)(4 * g + bb) * TT + t) * HHID + grow];
    }

    // ---- spin: ONE lane polls (bypass load), barrier releases the WG ----
    if (tid == 0) {
      const unsigned tgt = 16u * (unsigned)(t + 1);
      unsigned f;
      do {
        asm volatile("global_load_dword %0, %1, off sc0 sc1\n\t"
                     "s_waitcnt vmcnt(0)"
                     : "=v"(f) : "v"(cptr) : "memory");
      } while (f < tgt);
    }
    __syncthreads();

    // ---- stage th(t): coalesced bypass loads -> swizzled LDS ----
    const float* thsrc = th_buf + ((long)(t & 1) * 16 + g) * 4 * HHID;
    f32x4 c0, c1;
    load2_bypass(thsrc + 4 * tid, thsrc + 1024 + 4 * tid, c0, c1);

    float accH[32];
    // ---- Wih @ x (overlaps th load latency) ----
    if (t < TT) {
      float xv[4][2];
      #pragma unroll
      for (int b = 0; b < 4; ++b) {
        xv[b][0] = xi[b].x * (1.f + 0.01f * xn[b].x);
        xv[b][1] = xi[b].y * (1.f + 0.01f * xn[b].y);
      }
      #pragma unroll
      for (int r = 0; r < 8; ++r)
        #pragma unroll
        for (int b = 0; b < 4; ++b)
          accH[r * 4 + b] = wih[r].x * xv[b][0] + wih[r].y * xv[b][1];
    } else {
      #pragma unroll
      for (int i = 0; i < 32; ++i) accH[i] = 0.f;
    }

    asm volatile("s_waitcnt vmcnt(0)" : "+v"(c0), "+v"(c1) :: "memory");
    float* dst = lds_th[t & 1];
    *(f32x4*)&dst[stg0] = c0;
    *(f32x4*)&dst[stg1] = c1;
    __syncthreads();

    // ---- read th from LDS (b128, swizzle-conflict-free) ----
    const float* src = lds_th[t & 1];
    f32x4 tha[4], thb[4];
    #pragma unroll
    for (int b = 0; b < 4; ++b) {
      int f0 = (512 * b + 8 * l) ^ rsw;
      tha[b] = *(const f32x4*)&src[f0];
      thb[b] = *(const f32x4*)&src[f0 ^ 4];
    }

    // ---- Whh @ th ----
    if (t < TT) {
      #pragma unroll
      for (int r = 0; r < 8; ++r)
        #pragma unroll
        for (int b = 0; b < 4; ++b)
          accH[r * 4 + b] += whh[r][0].x * tha[b].x + whh[r][0].y * tha[b].y +
                             whh[r][0].z * tha[b].z + whh[r][0].w * tha[b].w +
                             whh[r][1].x * thb[b].x + whh[r][1].y * thb[b].y +
                             whh[r][1].z * thb[b].z + whh[r][1].w * thb[b].w;
      // ---- butterfly reduce: even lane l ends with value v=l>>1 ----
      #pragma unroll
      for (int rd = 0; rd < 5; ++rd) {
        const int m = 32 >> rd;
        const int half = 16 >> rd;
        const bool hi = (l & m) != 0;
        #pragma unroll
        for (int j = 0; j < half; ++j) {
          float send = hi ? accH[j] : accH[j + half];
          float recv = __shfl_xor(send, m, 64);
          accH[j] = (hi ? accH[j + half] : accH[j]) + recv;
        }
      }
      accH[0] += __shfl_xor(accH[0], 1, 64);

      // ---- h update + publish th(t+1) ----
      if (redlane) {
        float dh = -hreg + accH[0] + bhh_v + 0.01f * nre;
        hreg += 0.1f * dh;   // ALPHA = DT/TAU
        __hip_atomic_store(
            &th_buf[((((t + 1) & 1) * 16 + g) * 4 + bb) * HHID + grow],
            tanhf(hreg), __ATOMIC_RELAXED, __HIP_MEMORY_SCOPE_AGENT);
      }
      // ---- drain own stores; WG-level arrive; last wave bumps epoch ----
      asm volatile("s_waitcnt vmcnt(0)" ::: "memory");
      if (l == 0) {
        unsigned old = atomicAdd(&s_arrive, 1u);
        if ((old & 3u) == 3u)
          __hip_atomic_fetch_add(&cnt[g * 64], 1u, __ATOMIC_RELAXED,
                                 __HIP_MEMORY_SCOPE_AGENT);
      }
    }

    // ---- Who/out (off the inter-WG critical path) ----
    if (t > 0) {
      float accO[4];
      #pragma unroll
      for (int b = 0; b < 4; ++b)
        accO[b] = who0.x * tha[b].x + who0.y * tha[b].y +
                  who0.z * tha[b].z + who0.w * tha[b].w +
                  who1.x * thb[b].x + who1.y * thb[b].y +
                  who1.z * thb[b].z + who1.w * thb[b].w;
      {
        const bool hi = (l & 32) != 0;
        float s0 = hi ? accO[0] : accO[2];
        float s1 = hi ? accO[1] : accO[3];
        float r0 = __shfl_xor(s0, 32, 64);
        float r1 = __shfl_xor(s1, 32, 64);
        accO[0] = (hi ? accO[2] : accO[0]) + r0;
        accO[1] = (hi ? accO[3] : accO[1]) + r1;
      }
      {
        const bool hi = (l & 16) != 0;
        float s0 = hi ? accO[0] : accO[1];
        float r0 = __shfl_xor(s0, 16, 64);
        accO[0] = (hi ? accO[1] : accO[0]) + r0;
      }
      accO[0] += __shfl_xor(accO[0], 8, 64);
      accO[0] += __shfl_xor(accO[0], 4, 64);
      accO[0] += __shfl_xor(accO[0], 2, 64);
      accO[0] += __shfl_xor(accO[0], 1, 64);
      if (outlane) {
        long oof = (long)OUT_OFF + ((long)(4 * g + ob) * TT + (t - 1)) * OOUT + oc;
        out[oof] = accO[0] + bho_v;
      }
    }
  }

  // ---- final hidden state ----
  if (redlane)
    out[(long)(4 * g + bb) * HHID + grow] = hreg;
}

extern "C" void kernel_launch(void* const* d_in, const int* in_sizes, int n_in,
                              void* d_out, int out_size, void* d_ws, size_t ws_size,
                              hipStream_t stream) {
  const float* inputs  = (const float*)d_in[0];
  const float* hidden  = (const float*)d_in[1];
  const float* innoise = (const float*)d_in[2];
  const float* renoise = (const float*)d_in[3];
  const float* Wih     = (const float*)d_in[4];
  const float* Whh     = (const float*)d_in[5];
  const float* bhh     = (const float*)d_in[6];
  const float* Who     = (const float*)d_in[7];
  const float* bho     = (const float*)d_in[8];
  float* out = (float*)d_out;

  unsigned int* cnt = (unsigned int*)d_ws;              // [16] epochs, 256B stride
  float* th_buf = (float*)((char*)d_ws + 4096);         // [2][16][4][512] f32

  hipMemsetAsync(d_ws, 0, 4096, stream);                // reset epochs

  hipLaunchKernelGGL(rnn_kernel, dim3(256), dim3(NTHR), 0, stream,
                     inputs, hidden, innoise, renoise, Wih, Whh, bhh, Who, bho,
                     out, cnt, th_buf);
}

// Round 6
// 32259.073 us; speedup vs baseline: 1.0201x; 1.0201x over previous
//
#include <hip/hip_runtime.h>
#include <math.h>

// Problem sizes (fixed by reference)
#define TT 2048
#define IIN 128
#define HHID 512
#define OOUT 64
#define OUT_OFF (64 * HHID)   // h_final [B,H] then outs [B,T,O]

// 16 groups x 16 WGs. Group g owns batches 4g..4g+3. WG w owns h-rows
// [32w,32w+32) + Who rows [4w,4w+4). 4 waves/WG; wave wv owns 8 h-rows +
// Who row 4w+wv; lane l owns k-chunk [8l,8l+8). Weights in VGPRs.
//
// Protocol (all cross-WG ops are compiler-lowered relaxed AGENT atomics —
// R5 lesson: hand-rolled sc0/sc1 loads can be served stale-fast from near
// caches, turning the spin into eviction-luck; R2 lesson: no acquire/release
// fences in the loop; R4 lesson applies only jointly with this one):
//   publish: scalar atomic stores of tanh(h) -> th_buf[(t+1)&1]
//   drain:   __syncthreads (compiler emits vmcnt(0) before s_barrier)
//   arrive:  tid0 fetch_add(+1) on the group epoch counter
//   wait:    tid0 polls atomic load until cnt >= 16*(t+1); __syncthreads
//   consume: 4x u64 atomic loads/thread (coalesced) -> swizzled LDS -> b128
#define NTHR 256

typedef float f32x4 __attribute__((ext_vector_type(4)));

// scalar-float-index swizzle: XOR bits[2:4] with bits[5:7]
__device__ __forceinline__ int swzF(int f) {
  return f ^ (((f >> 5) & 7) << 2);
}

extern "C" __global__ void __launch_bounds__(NTHR, 1)
rnn_kernel(const float* __restrict__ inputs,
           const float* __restrict__ hidden,
           const float* __restrict__ in_noise,
           const float* __restrict__ re_noise,
           const float* __restrict__ Wih,
           const float* __restrict__ Whh,
           const float* __restrict__ bhh,
           const float* __restrict__ Who,
           const float* __restrict__ bho,
           float* __restrict__ out,
           unsigned int* __restrict__ cnt,    // [16] epoch counters, 64-dword stride
           float* __restrict__ th_buf)        // [2][16][4][512] f32
{
  __shared__ float lds_th[2][2048];   // double-buffered swizzled th tile

  const int tid = threadIdx.x;
  const int l  = tid & 63;
  const int wv = tid >> 6;               // wave 0..3
  const int g = blockIdx.x & 15;         // group (bid%16 -> XCD affinity, perf only)
  const int w = blockIdx.x >> 4;         // member 0..15
  const int j0 = w * 32;
  const int k0 = 8 * l;

  // ---------------- weights into registers (cached loads, once) ----------------
  f32x4 whh[8][2];
  float2 wih[8];
  #pragma unroll
  for (int r = 0; r < 8; ++r) {
    const float* wr = &Whh[(long)(j0 + 8 * wv + r) * HHID + k0];
    whh[r][0] = *(const f32x4*)wr;
    whh[r][1] = *(const f32x4*)(wr + 4);
    wih[r] = *(const float2*)&Wih[(long)(j0 + 8 * wv + r) * IIN + 2 * l];
  }
  const int oc = 4 * w + wv;
  f32x4 who0 = *(const f32x4*)&Who[(long)oc * HHID + k0];
  f32x4 who1 = *(const f32x4*)&Who[(long)oc * HHID + k0 + 4];
  const float bho_v = bho[oc];

  // ---------------- reduce-output lane mapping ----------------
  const bool redlane = (l & 1) == 0;
  const int v  = (l >> 1) & 31;
  const int rr = v >> 2;                 // local h row 0..7
  const int bb = v & 3;                  // batch
  const int grow = j0 + 8 * wv + rr;
  const int ob = (l >> 4) & 3;
  const bool outlane = (l & 15) == 0;

  float bhh_v = 0.f, hreg = 0.f;
  if (redlane) {
    bhh_v = bhh[grow];
    hreg = hidden[(long)(4 * g + bb) * HHID + grow];
    __hip_atomic_store(&th_buf[((0 * 16 + g) * 4 + bb) * HHID + grow],
                       tanhf(hreg), __ATOMIC_RELAXED, __HIP_MEMORY_SCOPE_AGENT);
  }
  __syncthreads();                       // vmcnt(0) drain per wave
  if (tid == 0)
    __hip_atomic_fetch_add(&cnt[g * 64], 1u, __ATOMIC_RELAXED,
                           __HIP_MEMORY_SCOPE_AGENT);

  // read swizzle XOR term: f0 = (512b + 8l) ^ rsw
  const int rsw = ((l >> 2) & 7) << 2;
  const unsigned int* cptr = &cnt[g * 64];

  for (int t = 0; t <= TT; ++t) {
    // ---- prefetch x / noise (cached loads; latency hidden under spin) ----
    float2 xi[4], xn[4];
    float nre = 0.f;
    if (t < TT) {
      #pragma unroll
      for (int b = 0; b < 4; ++b) {
        long off = ((long)(4 * g + b) * TT + t) * IIN + 2 * l;
        xi[b] = *(const float2*)&inputs[off];
        xn[b] = *(const float2*)&in_noise[off];
      }
      if (redlane)
        nre = re_noise[((long)(4 * g + bb) * TT + t) * HHID + grow];
    }

    // ---- spin: ONE lane polls (relaxed agent atomic), barrier releases WG ----
    if (tid == 0) {
      const unsigned tgt = 16u * (unsigned)(t + 1);
      while (__hip_atomic_load(cptr, __ATOMIC_RELAXED,
                               __HIP_MEMORY_SCOPE_AGENT) < tgt) { }
    }
    __syncthreads();

    // ---- stage th(t): 4x u64 atomic loads/thread (coalesced) ----
    const float* thsrc = th_buf + ((long)(t & 1) * 16 + g) * 4 * HHID;
    const unsigned long long* q = (const unsigned long long*)thsrc;
    unsigned long long qv[4];
    #pragma unroll
    for (int i = 0; i < 4; ++i)
      qv[i] = __hip_atomic_load(&q[tid + i * NTHR], __ATOMIC_RELAXED,
                                __HIP_MEMORY_SCOPE_AGENT);

    float accH[32];
    // ---- Wih @ x (overlaps th load latency) ----
    if (t < TT) {
      float xv[4][2];
      #pragma unroll
      for (int b = 0; b < 4; ++b) {
        xv[b][0] = xi[b].x * (1.f + 0.01f * xn[b].x);
        xv[b][1] = xi[b].y * (1.f + 0.01f * xn[b].y);
      }
      #pragma unroll
      for (int r = 0; r < 8; ++r)
        #pragma unroll
        for (int b = 0; b < 4; ++b)
          accH[r * 4 + b] = wih[r].x * xv[b][0] + wih[r].y * xv[b][1];
    } else {
      #pragma unroll
      for (int i = 0; i < 32; ++i) accH[i] = 0.f;
    }

    // ---- write staged th into swizzled LDS (float2 per u64) ----
    {
      float* dst = lds_th[t & 1];
      #pragma unroll
      for (int i = 0; i < 4; ++i) {
        int f = 2 * (tid + i * NTHR);
        int idx = f ^ (((f >> 5) & 7) << 2);
        float2 fv;
        fv.x = __uint_as_float((unsigned)(qv[i] & 0xffffffffu));
        fv.y = __uint_as_float((unsigned)(qv[i] >> 32));
        *(float2*)&dst[idx] = fv;
      }
    }
    __syncthreads();

    // ---- read th from LDS (b128, swizzle-conflict-free) ----
    const float* src = lds_th[t & 1];
    f32x4 tha[4], thb[4];
    #pragma unroll
    for (int b = 0; b < 4; ++b) {
      int f0 = (512 * b + 8 * l) ^ rsw;
      tha[b] = *(const f32x4*)&src[f0];
      thb[b] = *(const f32x4*)&src[f0 ^ 4];
    }

    // ---- Whh @ th ----
    if (t < TT) {
      #pragma unroll
      for (int r = 0; r < 8; ++r)
        #pragma unroll
        for (int b = 0; b < 4; ++b)
          accH[r * 4 + b] += whh[r][0].x * tha[b].x + whh[r][0].y * tha[b].y +
                             whh[r][0].z * tha[b].z + whh[r][0].w * tha[b].w +
                             whh[r][1].x * thb[b].x + whh[r][1].y * thb[b].y +
                             whh[r][1].z * thb[b].z + whh[r][1].w * thb[b].w;
      // ---- butterfly reduce: even lane l ends with value v=l>>1 ----
      #pragma unroll
      for (int rd = 0; rd < 5; ++rd) {
        const int m = 32 >> rd;
        const int half = 16 >> rd;
        const bool hi = (l & m) != 0;
        #pragma unroll
        for (int j = 0; j < half; ++j) {
          float send = hi ? accH[j] : accH[j + half];
          float recv = __shfl_xor(send, m, 64);
          accH[j] = (hi ? accH[j + half] : accH[j]) + recv;
        }
      }
      accH[0] += __shfl_xor(accH[0], 1, 64);

      // ---- h update + publish th(t+1) ----
      if (redlane) {
        float dh = -hreg + accH[0] + bhh_v + 0.01f * nre;
        hreg += 0.1f * dh;   // ALPHA = DT/TAU
        __hip_atomic_store(
            &th_buf[((((t + 1) & 1) * 16 + g) * 4 + bb) * HHID + grow],
            tanhf(hreg), __ATOMIC_RELAXED, __HIP_MEMORY_SCOPE_AGENT);
      }
      // ---- drain (barrier implies vmcnt(0)) + single epoch add ----
      __syncthreads();
      if (tid == 0)
        __hip_atomic_fetch_add(&cnt[g * 64], 1u, __ATOMIC_RELAXED,
                               __HIP_MEMORY_SCOPE_AGENT);
    }

    // ---- Who/out (off the inter-WG critical path) ----
    if (t > 0) {
      float accO[4];
      #pragma unroll
      for (int b = 0; b < 4; ++b)
        accO[b] = who0.x * tha[b].x + who0.y * tha[b].y +
                  who0.z * tha[b].z + who0.w * tha[b].w +
                  who1.x * thb[b].x + who1.y * thb[b].y +
                  who1.z * thb[b].z + who1.w * thb[b].w;
      {
        const bool hi = (l & 32) != 0;
        float s0 = hi ? accO[0] : accO[2];
        float s1 = hi ? accO[1] : accO[3];
        float r0 = __shfl_xor(s0, 32, 64);
        float r1 = __shfl_xor(s1, 32, 64);
        accO[0] = (hi ? accO[2] : accO[0]) + r0;
        accO[1] = (hi ? accO[3] : accO[1]) + r1;
      }
      {
        const bool hi = (l & 16) != 0;
        float s0 = hi ? accO[0] : accO[1];
        float r0 = __shfl_xor(s0, 16, 64);
        accO[0] = (hi ? accO[1] : accO[0]) + r0;
      }
      accO[0] += __shfl_xor(accO[0], 8, 64);
      accO[0] += __shfl_xor(accO[0], 4, 64);
      accO[0] += __shfl_xor(accO[0], 2, 64);
      accO[0] += __shfl_xor(accO[0], 1, 64);
      if (outlane) {
        long oof = (long)OUT_OFF + ((long)(4 * g + ob) * TT + (t - 1)) * OOUT + oc;
        out[oof] = accO[0] + bho_v;
      }
    }
  }

  // ---- final hidden state ----
  if (redlane)
    out[(long)(4 * g + bb) * HHID + grow] = hreg;
}

extern "C" void kernel_launch(void* const* d_in, const int* in_sizes, int n_in,
                              void* d_out, int out_size, void* d_ws, size_t ws_size,
                              hipStream_t stream) {
  const float* inputs  = (const float*)d_in[0];
  const float* hidden  = (const float*)d_in[1];
  const float* innoise = (const float*)d_in[2];
  const float* renoise = (const float*)d_in[3];
  const float* Wih     = (const float*)d_in[4];
  const float* Whh     = (const float*)d_in[5];
  const float* bhh     = (const float*)d_in[6];
  const float* Who     = (const float*)d_in[7];
  const float* bho     = (const float*)d_in[8];
  float* out = (float*)d_out;

  unsigned int* cnt = (unsigned int*)d_ws;              // [16] epochs, 256B stride
  float* th_buf = (float*)((char*)d_ws + 4096);         // [2][16][4][512] f32

  hipMemsetAsync(d_ws, 0, 4096, stream);                // reset epochs

  hipLaunchKernelGGL(rnn_kernel, dim3(256), dim3(NTHR), 0, stream,
                     inputs, hidden, innoise, renoise, Wih, Whh, bhh, Who, bho,
                     out, cnt, th_buf);
}

// Round 7
// 32226.065 us; speedup vs baseline: 1.0212x; 1.0010x over previous
//
#include <hip/hip_runtime.h>
#include <math.h>

// Problem sizes (fixed by reference)
#define TT 2048
#define IIN 128
#define HHID 512
#define OOUT 64
#define OUT_OFF (64 * HHID)   // h_final [B,H] then outs [B,T,O]

// 16 groups x 16 WGs. Group g owns batches 4g..4g+3. WG w owns h-rows
// [32w,32w+32) + Who rows [4w,4w+4). 4 waves/WG; wave wv owns 8 h-rows +
// Who row 4w+wv; lane l owns k-chunk [8l,8l+8). Weights in VGPRs.
//
// R7 single-variable test vs R6: add a 96KB LDS pad to force 1 WG/CU.
// Theory: R4-R6's 16KB LDS let the dispatcher pack 2 WGs/CU (R1's 119KB
// forbade it); doubled CUs run ~2x slow and every group barrier propagates
// the straggler pace device-wide (R2-R6 all show ~15ms absolute VALU time
// vs R1's 1.35ms, invariant to spin style => placement, not protocol).
//
// Protocol (unchanged from R6): relaxed AGENT atomics only; publish ->
// __syncthreads (vmcnt drain) -> tid0 fetch_add -> tid0 poll -> barrier ->
// coalesced u64 atomic loads -> swizzled LDS -> b128 reads.
#define NTHR 256

typedef float f32x4 __attribute__((ext_vector_type(4)));

// scalar-float-index swizzle: XOR bits[2:4] with bits[5:7]
__device__ __forceinline__ int swzF(int f) {
  return f ^ (((f >> 5) & 7) << 2);
}

extern "C" __global__ void __launch_bounds__(NTHR, 1)
rnn_kernel(const float* __restrict__ inputs,
           const float* __restrict__ hidden,
           const float* __restrict__ in_noise,
           const float* __restrict__ re_noise,
           const float* __restrict__ Wih,
           const float* __restrict__ Whh,
           const float* __restrict__ bhh,
           const float* __restrict__ Who,
           const float* __restrict__ bho,
           float* __restrict__ out,
           unsigned int* __restrict__ cnt,    // [16] epoch counters, 64-dword stride
           float* __restrict__ th_buf)        // [2][16][4][512] f32
{
  __shared__ float lds_th[2][2048];     // double-buffered swizzled th tile (16KB)
  __shared__ float lds_pad[24576];      // 96KB occupancy limiter: force 1 WG/CU

  const int tid = threadIdx.x;
  const int l  = tid & 63;
  const int wv = tid >> 6;               // wave 0..3
  const int g = blockIdx.x & 15;         // group (bid%16 -> XCD affinity, perf only)
  const int w = blockIdx.x >> 4;         // member 0..15
  const int j0 = w * 32;
  const int k0 = 8 * l;

  if (inputs == nullptr) lds_pad[tid] = 0.f;   // never true; keeps pad allocated

  // ---------------- weights into registers (cached loads, once) ----------------
  f32x4 whh[8][2];
  float2 wih[8];
  #pragma unroll
  for (int r = 0; r < 8; ++r) {
    const float* wr = &Whh[(long)(j0 + 8 * wv + r) * HHID + k0];
    whh[r][0] = *(const f32x4*)wr;
    whh[r][1] = *(const f32x4*)(wr + 4);
    wih[r] = *(const float2*)&Wih[(long)(j0 + 8 * wv + r) * IIN + 2 * l];
  }
  const int oc = 4 * w + wv;
  f32x4 who0 = *(const f32x4*)&Who[(long)oc * HHID + k0];
  f32x4 who1 = *(const f32x4*)&Who[(long)oc * HHID + k0 + 4];
  const float bho_v = bho[oc];

  // ---------------- reduce-output lane mapping ----------------
  const bool redlane = (l & 1) == 0;
  const int v  = (l >> 1) & 31;
  const int rr = v >> 2;                 // local h row 0..7
  const int bb = v & 3;                  // batch
  const int grow = j0 + 8 * wv + rr;
  const int ob = (l >> 4) & 3;
  const bool outlane = (l & 15) == 0;

  float bhh_v = 0.f, hreg = 0.f;
  if (redlane) {
    bhh_v = bhh[grow];
    hreg = hidden[(long)(4 * g + bb) * HHID + grow];
    __hip_atomic_store(&th_buf[((0 * 16 + g) * 4 + bb) * HHID + grow],
                       tanhf(hreg), __ATOMIC_RELAXED, __HIP_MEMORY_SCOPE_AGENT);
  }
  __syncthreads();                       // vmcnt(0) drain per wave
  if (tid == 0)
    __hip_atomic_fetch_add(&cnt[g * 64], 1u, __ATOMIC_RELAXED,
                           __HIP_MEMORY_SCOPE_AGENT);

  // read swizzle XOR term: f0 = (512b + 8l) ^ rsw
  const int rsw = ((l >> 2) & 7) << 2;
  const unsigned int* cptr = &cnt[g * 64];

  for (int t = 0; t <= TT; ++t) {
    // ---- prefetch x / noise (cached loads; latency hidden under spin) ----
    float2 xi[4], xn[4];
    float nre = 0.f;
    if (t < TT) {
      #pragma unroll
      for (int b = 0; b < 4; ++b) {
        long off = ((long)(4 * g + b) * TT + t) * IIN + 2 * l;
        xi[b] = *(const float2*)&inputs[off];
        xn[b] = *(const float2*)&in_noise[off];
      }
      if (redlane)
        nre = re_noise[((long)(4 * g + bb) * TT + t) * HHID + grow];
    }

    // ---- spin: ONE lane polls (relaxed agent atomic), barrier releases WG ----
    if (tid == 0) {
      const unsigned tgt = 16u * (unsigned)(t + 1);
      while (__hip_atomic_load(cptr, __ATOMIC_RELAXED,
                               __HIP_MEMORY_SCOPE_AGENT) < tgt) { }
    }
    __syncthreads();

    // ---- stage th(t): 4x u64 atomic loads/thread (coalesced) ----
    const float* thsrc = th_buf + ((long)(t & 1) * 16 + g) * 4 * HHID;
    const unsigned long long* q = (const unsigned long long*)thsrc;
    unsigned long long qv[4];
    #pragma unroll
    for (int i = 0; i < 4; ++i)
      qv[i] = __hip_atomic_load(&q[tid + i * NTHR], __ATOMIC_RELAXED,
                                __HIP_MEMORY_SCOPE_AGENT);

    float accH[32];
    // ---- Wih @ x (overlaps th load latency) ----
    if (t < TT) {
      float xv[4][2];
      #pragma unroll
      for (int b = 0; b < 4; ++b) {
        xv[b][0] = xi[b].x * (1.f + 0.01f * xn[b].x);
        xv[b][1] = xi[b].y * (1.f + 0.01f * xn[b].y);
      }
      #pragma unroll
      for (int r = 0; r < 8; ++r)
        #pragma unroll
        for (int b = 0; b < 4; ++b)
          accH[r * 4 + b] = wih[r].x * xv[b][0] + wih[r].y * xv[b][1];
    } else {
      #pragma unroll
      for (int i = 0; i < 32; ++i) accH[i] = 0.f;
    }

    // ---- write staged th into swizzled LDS (float2 per u64) ----
    {
      float* dst = lds_th[t & 1];
      #pragma unroll
      for (int i = 0; i < 4; ++i) {
        int f = 2 * (tid + i * NTHR);
        int idx = f ^ (((f >> 5) & 7) << 2);
        float2 fv;
        fv.x = __uint_as_float((unsigned)(qv[i] & 0xffffffffu));
        fv.y = __uint_as_float((unsigned)(qv[i] >> 32));
        *(float2*)&dst[idx] = fv;
      }
    }
    __syncthreads();

    // ---- read th from LDS (b128, swizzle-conflict-free) ----
    const float* src = lds_th[t & 1];
    f32x4 tha[4], thb[4];
    #pragma unroll
    for (int b = 0; b < 4; ++b) {
      int f0 = (512 * b + 8 * l) ^ rsw;
      tha[b] = *(const f32x4*)&src[f0];
      thb[b] = *(const f32x4*)&src[f0 ^ 4];
    }

    // ---- Whh @ th ----
    if (t < TT) {
      #pragma unroll
      for (int r = 0; r < 8; ++r)
        #pragma unroll
        for (int b = 0; b < 4; ++b)
          accH[r * 4 + b] += whh[r][0].x * tha[b].x + whh[r][0].y * tha[b].y +
                             whh[r][0].z * tha[b].z + whh[r][0].w * tha[b].w +
                             whh[r][1].x * thb[b].x + whh[r][1].y * thb[b].y +
                             whh[r][1].z * thb[b].z + whh[r][1].w * thb[b].w;
      // ---- butterfly reduce: even lane l ends with value v=l>>1 ----
      #pragma unroll
      for (int rd = 0; rd < 5; ++rd) {
        const int m = 32 >> rd;
        const int half = 16 >> rd;
        const bool hi = (l & m) != 0;
        #pragma unroll
        for (int j = 0; j < half; ++j) {
          float send = hi ? accH[j] : accH[j + half];
          float recv = __shfl_xor(send, m, 64);
          accH[j] = (hi ? accH[j + half] : accH[j]) + recv;
        }
      }
      accH[0] += __shfl_xor(accH[0], 1, 64);

      // ---- h update + publish th(t+1) ----
      if (redlane) {
        float dh = -hreg + accH[0] + bhh_v + 0.01f * nre;
        hreg += 0.1f * dh;   // ALPHA = DT/TAU
        __hip_atomic_store(
            &th_buf[((((t + 1) & 1) * 16 + g) * 4 + bb) * HHID + grow],
            tanhf(hreg), __ATOMIC_RELAXED, __HIP_MEMORY_SCOPE_AGENT);
      }
      // ---- drain (barrier implies vmcnt(0)) + single epoch add ----
      __syncthreads();
      if (tid == 0)
        __hip_atomic_fetch_add(&cnt[g * 64], 1u, __ATOMIC_RELAXED,
                               __HIP_MEMORY_SCOPE_AGENT);
    }

    // ---- Who/out (off the inter-WG critical path) ----
    if (t > 0) {
      float accO[4];
      #pragma unroll
      for (int b = 0; b < 4; ++b)
        accO[b] = who0.x * tha[b].x + who0.y * tha[b].y +
                  who0.z * tha[b].z + who0.w * tha[b].w +
                  who1.x * thb[b].x + who1.y * thb[b].y +
                  who1.z * thb[b].z + who1.w * thb[b].w;
      {
        const bool hi = (l & 32) != 0;
        float s0 = hi ? accO[0] : accO[2];
        float s1 = hi ? accO[1] : accO[3];
        float r0 = __shfl_xor(s0, 32, 64);
        float r1 = __shfl_xor(s1, 32, 64);
        accO[0] = (hi ? accO[2] : accO[0]) + r0;
        accO[1] = (hi ? accO[3] : accO[1]) + r1;
      }
      {
        const bool hi = (l & 16) != 0;
        float s0 = hi ? accO[0] : accO[1];
        float r0 = __shfl_xor(s0, 16, 64);
        accO[0] = (hi ? accO[1] : accO[0]) + r0;
      }
      accO[0] += __shfl_xor(accO[0], 8, 64);
      accO[0] += __shfl_xor(accO[0], 4, 64);
      accO[0] += __shfl_xor(accO[0], 2, 64);
      accO[0] += __shfl_xor(accO[0], 1, 64);
      if (outlane) {
        long oof = (long)OUT_OFF + ((long)(4 * g + ob) * TT + (t - 1)) * OOUT + oc;
        out[oof] = accO[0] + bho_v;
      }
    }
  }

  // ---- final hidden state ----
  if (redlane)
    out[(long)(4 * g + bb) * HHID + grow] = hreg;
}

extern "C" void kernel_launch(void* const* d_in, const int* in_sizes, int n_in,
                              void* d_out, int out_size, void* d_ws, size_t ws_size,
                              hipStream_t stream) {
  const float* inputs  = (const float*)d_in[0];
  const float* hidden  = (const float*)d_in[1];
  const float* innoise = (const float*)d_in[2];
  const float* renoise = (const float*)d_in[3];
  const float* Wih     = (const float*)d_in[4];
  const float* Whh     = (const float*)d_in[5];
  const float* bhh     = (const float*)d_in[6];
  const float* Who     = (const float*)d_in[7];
  const float* bho     = (const float*)d_in[8];
  float* out = (float*)d_out;

  unsigned int* cnt = (unsigned int*)d_ws;              // [16] epochs, 256B stride
  float* th_buf = (float*)((char*)d_ws + 4096);         // [2][16][4][512] f32

  hipMemsetAsync(d_ws, 0, 4096, stream);                // reset epochs

  hipLaunchKernelGGL(rnn_kernel, dim3(256), dim3(NTHR), 0, stream,
                     inputs, hidden, innoise, renoise, Wih, Whh, bhh, Who, bho,
                     out, cnt, th_buf);
}